// Round 1
// baseline (937.408 us; speedup 1.0000x reference)
//
#include <hip/hip_runtime.h>
#include <stdint.h>

// RNN car-following model: 256 sequential steps, 4096 independent vehicles.
// One WG (256 thr / 4 waves) owns 16 vehicles for all steps; everything lives
// in LDS; CNN stages run on bf16 MFMA (16x16x32) with M=vehicle.
// State (pos/speed rings) kept fp32, pre-scaled (pos*0.005, spd*0.025) so the
// CNN input build is subtract/copy only. x0 is split hi+lo bf16 (k=12..14
// carry the lo part with duplicated ci=0 weights) for ~16-bit input precision.

#define PAST 25

typedef __attribute__((ext_vector_type(8))) short bf16x8;
typedef __attribute__((ext_vector_type(4))) float f32x4;

#define MFMA16x16x32 __builtin_amdgcn_mfma_f32_16x16x32_bf16

__device__ __forceinline__ uint16_t f2bf(float f) {
  union { float f; uint32_t u; } x; x.f = f;
  return (uint16_t)((x.u + 0x7FFFu + ((x.u >> 16) & 1u)) >> 16);
}
__device__ __forceinline__ float bf2f(uint32_t bits) {
  union { uint32_t u; float f; } x; x.u = bits << 16;
  return x.f;
}

union FragU { bf16x8 v; short e[8]; uint16_t u[8]; uint4 q; };

// LDS: 18240+2112+2112+12800+13312+12544+2560 = 63680 B  (<= 64KB)
struct __align__(16) SMem {
  uint32_t lead[16][285];      // (lp_bf16*0.005) | (ls_bf16*0.025)<<16 ; pitch 285 for bank stagger
  float posr[16][33];          // pos ring (scaled *0.005), slot = (t+q)&31 ; pitch 33
  float spdr[16][33];          // spd ring (scaled *0.025)
  uint32_t Xim[25][16][8];     // im2col rows: 16 bf16 k-slots per (p,v); A-frag = ds_read_b128
  uint16_t pool1[13][16][32];  // bf16 [row][veh][ci]  (64B/veh row -> aligned b128 A-frags)
  uint16_t pool2[16][392];     // bf16 [veh][384 flat + pad to 392 (784B, 16B-mult, bank stagger)]
  float dpart[4][16][10];      // dense2 partials per wave
};

__global__ __launch_bounds__(256, 1) void rnncf_kernel(
    const float* __restrict__ lead_states, const float* __restrict__ cur_states,
    const float* __restrict__ conv1_w, const float* __restrict__ conv1_b,
    const float* __restrict__ conv2_w, const float* __restrict__ conv2_b,
    const float* __restrict__ dense2_w, const float* __restrict__ dense2_b,
    const float* __restrict__ dense1_w, const float* __restrict__ dense1_b,
    float* __restrict__ out, int nt, int ntw) {
  __shared__ SMem sm;
  const int tid = threadIdx.x;
  const int lane = tid & 63;
  const int wid = tid >> 6;
  const int n = lane & 15;         // MFMA col lane (cout / o) and A-row vehicle for frag loads
  const int quad = lane >> 4;
  const int vbase = blockIdx.x * 16;
  const f32x4 vzero = {0.f, 0.f, 0.f, 0.f};

  // ---------------- init: LDS preload ----------------
  for (int idx = tid; idx < 16 * ntw; idx += 256) {
    int v = idx / ntw, i = idx - v * ntw;
    const float2 l = *(const float2*)(lead_states + ((size_t)(vbase + v) * ntw + i) * 2);
    uint32_t lp = f2bf(l.x * 0.005f);
    uint32_t ls = f2bf(l.y * 0.025f);
    sm.lead[v][i] = lp | (ls << 16);
  }
  for (int idx = tid; idx < 16 * PAST; idx += 256) {
    int v = idx / PAST, q = idx - v * PAST;
    const float2 c = *(const float2*)(cur_states + ((size_t)(vbase + v) * PAST + q) * 2);
    sm.posr[v][q] = c.x * 0.005f;
    sm.spdr[v][q] = c.y * 0.025f;
  }

  // ---------------- init: weight fragments (persistent VGPRs) ----------------
  // conv1: K slots k = ci*4 + dw ; ci==3 group duplicates ci=0 weights (x0_lo path)
  FragU B1[2];
#pragma unroll
  for (int ct = 0; ct < 2; ++ct) {
#pragma unroll
    for (int jj = 0; jj < 8; ++jj) {
      int k = quad * 8 + jj;
      int dw = k & 3, cig = k >> 2;
      float w = 0.f;
      if (k < 16 && dw < 3) {
        int ci = (cig == 3) ? 0 : cig;
        w = conv1_w[(dw * 3 + ci) * 32 + ct * 16 + n];
      }
      B1[ct].u[jj] = f2bf(w);
    }
  }
  // conv2: k = dw*32 + ci exactly matches (3,32,64) layout
  FragU B2[3][4];
#pragma unroll
  for (int dw = 0; dw < 3; ++dw)
#pragma unroll
    for (int ct = 0; ct < 4; ++ct)
#pragma unroll
      for (int jj = 0; jj < 8; ++jj) {
        int ci = quad * 8 + jj;
        B2[dw][ct].u[jj] = f2bf(conv2_w[(dw * 32 + ci) * 64 + ct * 16 + n]);
      }
  // dense2: this wave owns ktiles 3w..3w+2 ; N=10 padded to 16 with zeros
  FragU Bd[3];
#pragma unroll
  for (int i = 0; i < 3; ++i)
#pragma unroll
    for (int jj = 0; jj < 8; ++jj) {
      int k = (wid * 3 + i) * 32 + quad * 8 + jj;
      Bd[i].u[jj] = f2bf((n < 10) ? dense2_w[k * 10 + n] : 0.f);
    }
  const float b1v0 = conv1_b[n], b1v1 = conv1_b[16 + n];
  float b2v[4];
#pragma unroll
  for (int ct = 0; ct < 4; ++ct) b2v[ct] = conv2_b[ct * 16 + n];
  const float d2bv = (n < 10) ? dense2_b[n] : 0.f;
  const float wd1v = (n < 10) ? dense1_w[n] : 0.f;
  const float bd1v = dense1_b[0];

  __syncthreads();

  // conv2 pair job: computes out2 rows jA,jB for all 4 c-tiles (A-frag reused
  // across ctiles), fuses relu+bias+maxpool in regs, writes pool2 row jp.
  auto conv2_pair = [&](int jA, int jB, int jp) {
    f32x4 accA[4], accB[4];
#pragma unroll
    for (int ct = 0; ct < 4; ++ct) { accA[ct] = vzero; accB[ct] = vzero; }
#pragma unroll
    for (int dw = 0; dw < 3; ++dw) {
      FragU a;
      a.q = *(const uint4*)(&sm.pool1[jA + dw][n][quad * 8]);
#pragma unroll
      for (int ct = 0; ct < 4; ++ct)
        accA[ct] = MFMA16x16x32(a.v, B2[dw][ct].v, accA[ct], 0, 0, 0);
    }
    if (jB >= 0) {
#pragma unroll
      for (int dw = 0; dw < 3; ++dw) {
        FragU a;
        a.q = *(const uint4*)(&sm.pool1[jB + dw][n][quad * 8]);
#pragma unroll
        for (int ct = 0; ct < 4; ++ct)
          accB[ct] = MFMA16x16x32(a.v, B2[dw][ct].v, accB[ct], 0, 0, 0);
      }
    }
#pragma unroll
    for (int ct = 0; ct < 4; ++ct) {
#pragma unroll
      for (int r = 0; r < 4; ++r) {
        float va = accA[ct][r];
        float vb = (jB >= 0) ? accB[ct][r] : va;
        float m = fmaxf(fmaxf(va, vb) + b2v[ct], 0.f);
        sm.pool2[quad * 4 + r][jp * 64 + ct * 16 + n] = f2bf(m);
      }
    }
  };

  // ---------------- 256 sequential steps ----------------
  for (int t = 0; t < nt; ++t) {
    // ---- stage 1: build Xim (im2col, bf16, fragment-layout rows) ----
#pragma unroll
    for (int rep = 0; rep < 2; ++rep) {
      int pi = tid + rep * 256;
      if (pi < 400) {
        int v = pi & 15, p = pi >> 4;
        uint16_t hi[3], lo[3], x1b[3];
        uint32_t x2b[3];
#pragma unroll
        for (int dw = 0; dw < 3; ++dw) {
          int q = p - 1 + dw;                   // x-row index; SAME-pad at q<0 or q>24
          bool ok = (q >= 0) && (q <= 24);
          int u = t + (ok ? q : 0);
          uint32_t lw = sm.lead[v][u];
          float cp = sm.posr[v][u & 31];
          float cs = sm.spdr[v][u & 31];
          float x0 = ok ? (bf2f(lw & 0xffffu) - cp) : 0.f;   // (lead_pos-pos)/200 (pre-scaled)
          uint16_t h = f2bf(x0);
          hi[dw] = h;
          lo[dw] = f2bf(x0 - bf2f((uint32_t)h));             // x0 lo-part
          x1b[dw] = f2bf(ok ? cs : 0.f);                     // spd/40 (pre-scaled)
          x2b[dw] = ok ? (lw >> 16) : 0u;                    // lead_spd/40 already bf16
        }
        uint32_t* Xw = sm.Xim[p][v];
        Xw[0] = (uint32_t)hi[0] | ((uint32_t)hi[1] << 16);   // k0,k1
        Xw[1] = (uint32_t)hi[2];                             // k2 (k3=0)
        Xw[2] = (uint32_t)x1b[0] | ((uint32_t)x1b[1] << 16); // k4,k5
        Xw[3] = (uint32_t)x1b[2];                            // k6
        Xw[4] = x2b[0] | (x2b[1] << 16);                     // k8,k9
        Xw[5] = x2b[2];                                      // k10
        Xw[6] = (uint32_t)lo[0] | ((uint32_t)lo[1] << 16);   // k12,k13 (x0 lo)
        Xw[7] = (uint32_t)lo[2];                             // k14
      }
    }
    __syncthreads();

    // ---- stage 2: conv1 (MFMA) + relu + maxpool -> pool1 ----
#pragma unroll
    for (int i = 0; i < 4; ++i) {
      int pp = wid + 4 * i;            // wave-uniform; pp=12 only on wave 0
      if (pp <= 12) {
        int p0 = 2 * pp;
        int p1 = (pp == 12) ? p0 : p0 + 1;
        FragU a0, a1;
        a0.q = *(const uint4*)(&sm.Xim[p0][n][(quad & 1) * 4]);
        a1.q = *(const uint4*)(&sm.Xim[p1][n][(quad & 1) * 4]);
        if (quad >= 2) { a0.q = make_uint4(0u, 0u, 0u, 0u); a1.q = make_uint4(0u, 0u, 0u, 0u); }
#pragma unroll
        for (int ct = 0; ct < 2; ++ct) {
          f32x4 d0 = vzero, d1 = vzero;
          d0 = MFMA16x16x32(a0.v, B1[ct].v, d0, 0, 0, 0);
          d1 = MFMA16x16x32(a1.v, B1[ct].v, d1, 0, 0, 0);
          float bv = ct ? b1v1 : b1v0;
#pragma unroll
          for (int r = 0; r < 4; ++r) {
            float m = fmaxf(fmaxf(d0[r], d1[r]) + bv, 0.f);
            sm.pool1[pp][quad * 4 + r][ct * 16 + n] = f2bf(m);
          }
        }
      }
    }
    __syncthreads();

    // ---- stage 3: conv2 (MFMA, A reused over 4 ctiles) + relu + pool -> pool2 ----
    conv2_pair(2 * wid, 2 * wid + 1, wid);     // pairs (0,1)(2,3)(4,5)(6,7) -> jp 0..3
    if (wid == 0) conv2_pair(8, 9, 4);         // pair (8,9) -> jp4
    if (wid == 1) conv2_pair(10, -1, 5);       // singleton 10 -> jp5
    __syncthreads();

    // ---- stage 4: dense2 partials (each wave: 3 of 12 ktiles) ----
    {
      f32x4 acc = vzero;
#pragma unroll
      for (int i = 0; i < 3; ++i) {
        FragU a;
        a.q = *(const uint4*)(&sm.pool2[n][(wid * 3 + i) * 32 + quad * 8]);
        acc = MFMA16x16x32(a.v, Bd[i].v, acc, 0, 0, 0);
      }
      if (n < 10) {
#pragma unroll
        for (int r = 0; r < 4; ++r) sm.dpart[wid][quad * 4 + r][n] = acc[r];
      }
    }
    __syncthreads();

    // ---- stage 5: reduce + relu + dense1 + acc + state update + output ----
    {
      int vv = tid >> 4;          // vehicle 0..15
      int o = tid & 15;           // dense2 output unit
      float contrib = 0.f;
      if (o < 10) {
        float s = sm.dpart[0][vv][o] + sm.dpart[1][vv][o] +
                  sm.dpart[2][vv][o] + sm.dpart[3][vv][o];
        contrib = fmaxf(s + d2bv, 0.f) * wd1v;
      }
      contrib += __shfl_xor(contrib, 1, 64);
      contrib += __shfl_xor(contrib, 2, 64);
      contrib += __shfl_xor(contrib, 4, 64);
      contrib += __shfl_xor(contrib, 8, 64);
      if (o == 0) {
        float accv = 10.f * (contrib + bd1v) - 6.f;          // (MAXA-MINA)*x + MINA
        int u24 = (t + 24) & 31;
        float ps = sm.posr[vv][u24];                         // scaled pos
        float ss = sm.spdr[vv][u24];                         // scaled spd
        float np = ps + 0.02f * ss;                          // pos + DT*spd (scaled units)
        float nsp = ss * 40.f + 0.1f * accv;                 // raw speed update
        sm.posr[vv][(t + 25) & 31] = np;
        sm.spdr[vv][(t + 25) & 31] = nsp * 0.025f;
        float2 o2;
        o2.x = np * 200.f;                                   // raw pos
        o2.y = nsp;
        *(float2*)(out + ((size_t)(vbase + vv) * nt + t) * 2) = o2;
      }
    }
    __syncthreads();
  }
}

extern "C" void kernel_launch(void* const* d_in, const int* in_sizes, int n_in,
                              void* d_out, int out_size, void* d_ws, size_t ws_size,
                              hipStream_t stream) {
  const float* lead = (const float*)d_in[0];
  const float* cur  = (const float*)d_in[1];
  // d_in[2] = mask (unused by reference)
  const float* c1w = (const float*)d_in[3];
  const float* c1b = (const float*)d_in[4];
  const float* c2w = (const float*)d_in[5];
  const float* c2b = (const float*)d_in[6];
  const float* d2w = (const float*)d_in[7];
  const float* d2b = (const float*)d_in[8];
  const float* d1w = (const float*)d_in[9];
  const float* d1b = (const float*)d_in[10];
  float* out = (float*)d_out;

  int nveh = in_sizes[1] / (PAST * 2);   // 4096
  int ntw  = in_sizes[2] / nveh;         // 280 = nt + PAST - 1
  int nt   = ntw - PAST + 1;             // 256
  int nblocks = nveh / 16;               // 256

  rnncf_kernel<<<nblocks, 256, 0, stream>>>(lead, cur, c1w, c1b, c2w, c2b,
                                            d2w, d2b, d1w, d1b, out, nt, ntw);
}

// Round 2
// 589.600 us; speedup vs baseline: 1.5899x; 1.5899x over previous
//
#include <hip/hip_runtime.h>
#include <stdint.h>

// RNN car-following model, 256 sequential steps x 4096 vehicles.
// One WG (512 thr / 8 waves) owns 16 vehicles for all steps.
// Round-2 design:
//  - Xcol ring: x-columns are static per absolute index u -> build each ONCE
//    (16 new values/step by state-writer lanes), stage1 is a v_perm repack.
//  - merged stage1+2 (each wave builds the Xim rows it consumes) -> 4 barriers.
//  - K-permuted pool1 (kappa=2n+ct) / pool2 (kappa2=4n+ct) so epilogue stores
//    are packed b32/b64; B-fragments permuted to match at init.
//  - bias folded into MFMA acc init; conv2 balanced (max 24 MFMA/wave);
//    rows 8/9 pooled at dense2 A-load via packed-u16 max (valid post-relu).

#define PAST 25

typedef __attribute__((ext_vector_type(8))) short bf16x8;
typedef __attribute__((ext_vector_type(4))) float f32x4;
#define MFMA16 __builtin_amdgcn_mfma_f32_16x16x32_bf16

static __device__ __forceinline__ uint32_t f2bf(float f) {
  union { float f; uint32_t u; } x; x.f = f;
  return (x.u + 0x7FFFu + ((x.u >> 16) & 1u)) >> 16;
}
static __device__ __forceinline__ float bf2f(uint32_t b) {
  union { uint32_t u; float f; } x; x.u = b << 16; return x.f;
}
static __device__ __forceinline__ uint32_t pkbf(float lo, float hi) {
  return f2bf(lo) | (f2bf(hi) << 16);
}
static __device__ __forceinline__ f32x4 bcast4(float v) {
  f32x4 r = {v, v, v, v}; return r;
}
// per-dword max of two packed bf16 pairs; valid because relu'd bf16 bit
// patterns of non-negative floats are monotone as u16
static __device__ __forceinline__ uint32_t pk_umax16(uint32_t a, uint32_t b) {
  uint32_t al = a << 16, bl = b << 16;
  uint32_t lo = (al > bl ? al : bl) >> 16;
  uint32_t ah = a & 0xffff0000u, bh = b & 0xffff0000u;
  uint32_t hi = ah > bh ? ah : bh;
  return lo | hi;
}

union FragU { bf16x8 v; uint16_t u[8]; uint4 q; };

// LDS: 4352 + 20000 + 16640 + 12544 + 4096 + 6144 = 63776 B
struct __align__(16) SMem {
  uint32_t Xcol[16][34][2];   // ring of x-columns: c0 = x0hi|x1<<16, c1 = x2|x0lo<<16
  uint32_t Xim[25 * 200];     // row p at p*200 dwords; veh v at +v*12; halves h*4
  uint16_t pool1[13][16][40]; // conv1 pooled, kappa=2n+ct, 80B vehicle rows
  uint16_t pool2[16][392];    // kappa2 = jp*64 + 4n + ct, 784B vehicle rows
  uint16_t raw2[2][16][64];   // un-pooled conv2 rows j=8,9 (128B vehicle rows)
  float dpart[8][16][12];     // dense2 partials (8 waves)
};

__global__ __launch_bounds__(512, 1) void rnncf_kernel(
    const float* __restrict__ lead_states, const float* __restrict__ cur_states,
    const float* __restrict__ conv1_w, const float* __restrict__ conv1_b,
    const float* __restrict__ conv2_w, const float* __restrict__ conv2_b,
    const float* __restrict__ dense2_w, const float* __restrict__ dense2_b,
    const float* __restrict__ dense1_w, const float* __restrict__ dense1_b,
    float* __restrict__ out, int nt, int ntw) {
  __shared__ SMem sm;
  const int tid = threadIdx.x;
  const int lane = tid & 63;
  const int wid = tid >> 6;           // 0..7
  const int n = lane & 15;            // MFMA col lane / A-row vehicle for frags
  const int quad = lane >> 4;
  const int vbase = blockIdx.x * 16;

  // ---------------- init: x-column ring u=0..24 ----------------
  if (tid < 400) {
    int v = tid & 15, u = tid >> 4;
    const float2 l = *(const float2*)(lead_states + ((size_t)(vbase + v) * ntw + u) * 2);
    const float2 c = *(const float2*)(cur_states + ((size_t)(vbase + v) * PAST + u) * 2);
    float x0 = (l.x - c.x) * 0.005f;
    uint32_t hi = f2bf(x0);
    uint32_t lo = f2bf(x0 - bf2f(hi));
    sm.Xcol[v][u][0] = hi | (f2bf(c.y * 0.025f) << 16);
    sm.Xcol[v][u][1] = f2bf(l.y * 0.025f) | (lo << 16);
  }
  // writer-lane persistent state (scaled: pos*0.005, spd*0.025)
  const bool is_writer = (tid < 256) && ((tid & 15) == 0);
  const int vv = tid >> 4;            // vehicle for stage5 lanes (tid<256)
  float pos_s = 0.f, spd_s = 0.f;
  if (is_writer) {
    const float2 c = *(const float2*)(cur_states + ((size_t)(vbase + vv) * PAST + PAST - 1) * 2);
    pos_s = c.x * 0.005f; spd_s = c.y * 0.025f;
  }

  // ---------------- init: weight fragments ----------------
  // conv1: k = cig*4+dw (cig order: x0hi, x1, x2, x0lo); zero for k>=16
  FragU B1[2];
#pragma unroll
  for (int ct = 0; ct < 2; ++ct)
#pragma unroll
    for (int jj = 0; jj < 8; ++jj) {
      int k = quad * 8 + jj;
      int dw = k & 3, cig = (k >> 2) & 3;
      float w = 0.f;
      if (k < 16 && dw < 3) {
        int ci = (cig == 3) ? 0 : cig;
        w = conv1_w[(dw * 3 + ci) * 32 + ct * 16 + n];
      }
      B1[ct].u[jj] = (uint16_t)f2bf(w);
    }
  // conv2: kappa -> ci_orig = (kappa&1)*16 + (kappa>>1)
  FragU B2[3][4];
#pragma unroll
  for (int dw = 0; dw < 3; ++dw)
#pragma unroll
    for (int ct = 0; ct < 4; ++ct)
#pragma unroll
      for (int jj = 0; jj < 8; ++jj) {
        int kap = quad * 8 + jj;
        int ci = (kap & 1) * 16 + (kap >> 1);
        B2[dw][ct].u[jj] = (uint16_t)f2bf(conv2_w[(dw * 32 + ci) * 64 + ct * 16 + n]);
      }
  // dense2: waves 0-3 own ktiles {2w,2w+1}; waves 4-7 own {4+w}
  const int nkt = (wid < 4) ? 2 : 1;
  FragU Bd[2];
#pragma unroll
  for (int i = 0; i < 2; ++i)
    if (i < nkt) {
      int kt = (wid < 4) ? (2 * wid + i) : (4 + wid);
#pragma unroll
      for (int jj = 0; jj < 8; ++jj) {
        int flat = kt * 32 + quad * 8 + jj;
        int jp = flat >> 6, rem = flat & 63;
        int cout2 = (rem & 3) * 16 + (rem >> 2);
        Bd[i].u[jj] = (uint16_t)f2bf((n < 10) ? dense2_w[(jp * 64 + cout2) * 10 + n] : 0.f);
      }
    }
  const float b1v[2] = {conv1_b[n], conv1_b[16 + n]};
  float b2v[4];
#pragma unroll
  for (int ct = 0; ct < 4; ++ct) b2v[ct] = conv2_b[ct * 16 + n];
  const float d2bv = (n < 10) ? dense2_b[n] : 0.f;
  const float wd1v = (n < 10) ? dense1_w[n] : 0.f;
  const float bd1v = dense1_b[0];

  __syncthreads();

  // ---------------- sequential steps ----------------
  const int dlt = lane >> 5;          // build: selects p0/p1
  const int h = (lane >> 4) & 1;      // build: dword half (c0 vs c1)
  const int v = lane & 15;            // build: vehicle

  for (int t = 0; t < nt; ++t) {
    // prefetch next lead sample (consumed in stage 5)
    const int u_new = t + PAST;
    float2 lead_nxt;
    if (is_writer) {
      int ui = (u_new < ntw) ? u_new : (ntw - 1);
      lead_nxt = *(const float2*)(lead_states + ((size_t)(vbase + vv) * ntw + ui) * 2);
    }

    // ---- stage 1+2 fused: build Xim rows + conv1 + relu/pool -> pool1 ----
    const int npp = (wid < 5) ? 2 : 1;
    for (int jo = 0; jo < npp; ++jo) {
      int pp = wid + 8 * jo;          // 0..12
      {
        int p = 2 * pp + dlt; if (p > 24) p = 24;
        int um1 = (t + p + 31) & 31;
        int u0 = (t + p) & 31;
        int up1 = (t + p + 1) & 31;
        uint32_t c0 = (p > 0) ? sm.Xcol[v][um1][h] : 0u;
        uint32_t c1 = sm.Xcol[v][u0][h];
        uint32_t c2 = (p < 24) ? sm.Xcol[v][up1][h] : 0u;
        uint4 w4;
        w4.x = __builtin_amdgcn_perm(c1, c0, 0x05040100u);  // lo16(c0)|lo16(c1)<<16
        w4.y = c2 & 0xffffu;
        w4.z = __builtin_amdgcn_perm(c1, c0, 0x07060302u);  // hi16(c0)|hi16(c1)<<16
        w4.w = c2 >> 16;
        *(uint4*)(&sm.Xim[p * 200 + v * 12 + h * 4]) = w4;
      }
      int p0 = 2 * pp;
      int p1 = (p0 + 1 > 24) ? 24 : p0 + 1;
      FragU a0, a1;
      a0.q = *(const uint4*)(&sm.Xim[p0 * 200 + n * 12 + (quad & 1) * 4]);
      a1.q = *(const uint4*)(&sm.Xim[p1 * 200 + n * 12 + (quad & 1) * 4]);
      f32x4 e0, e1;
      {
        f32x4 d0 = MFMA16(a0.v, B1[0].v, bcast4(b1v[0]), 0, 0, 0);
        f32x4 d1 = MFMA16(a1.v, B1[0].v, bcast4(b1v[0]), 0, 0, 0);
#pragma unroll
        for (int r = 0; r < 4; ++r) e0[r] = fmaxf(fmaxf(d0[r], d1[r]), 0.f);
      }
      {
        f32x4 d0 = MFMA16(a0.v, B1[1].v, bcast4(b1v[1]), 0, 0, 0);
        f32x4 d1 = MFMA16(a1.v, B1[1].v, bcast4(b1v[1]), 0, 0, 0);
#pragma unroll
        for (int r = 0; r < 4; ++r) e1[r] = fmaxf(fmaxf(d0[r], d1[r]), 0.f);
      }
#pragma unroll
      for (int r = 0; r < 4; ++r) {
        int veh = quad * 4 + r;
        *(uint32_t*)(&sm.pool1[pp][veh][2 * n]) = pkbf(e0[r], e1[r]);
      }
    }
    __syncthreads();

    // ---- stage 3: conv2 + relu (+pool for pairs) ----
    if (wid < 4) {                     // pooled pairs jp=0..3 (rows 2w,2w+1)
      int jA = 2 * wid, jB = jA + 1, jp = wid;
      f32x4 accA[4], accB[4];
#pragma unroll
      for (int ct = 0; ct < 4; ++ct) { accA[ct] = bcast4(b2v[ct]); accB[ct] = bcast4(b2v[ct]); }
#pragma unroll
      for (int dw = 0; dw < 3; ++dw) {
        FragU a;
        a.q = *(const uint4*)(&sm.pool1[jA + dw][n][quad * 8]);
#pragma unroll
        for (int ct = 0; ct < 4; ++ct) accA[ct] = MFMA16(a.v, B2[dw][ct].v, accA[ct], 0, 0, 0);
      }
#pragma unroll
      for (int dw = 0; dw < 3; ++dw) {
        FragU a;
        a.q = *(const uint4*)(&sm.pool1[jB + dw][n][quad * 8]);
#pragma unroll
        for (int ct = 0; ct < 4; ++ct) accB[ct] = MFMA16(a.v, B2[dw][ct].v, accB[ct], 0, 0, 0);
      }
#pragma unroll
      for (int r = 0; r < 4; ++r) {
        int veh = quad * 4 + r;
        float m0 = fmaxf(fmaxf(accA[0][r], accB[0][r]), 0.f);
        float m1 = fmaxf(fmaxf(accA[1][r], accB[1][r]), 0.f);
        float m2 = fmaxf(fmaxf(accA[2][r], accB[2][r]), 0.f);
        float m3 = fmaxf(fmaxf(accA[3][r], accB[3][r]), 0.f);
        uint2 w2; w2.x = pkbf(m0, m1); w2.y = pkbf(m2, m3);
        *(uint2*)(&sm.pool2[veh][jp * 64 + 4 * n]) = w2;
      }
    } else if (wid < 7) {              // singles j=8,9 (raw) and j=10 (jp5)
      int j = 4 + wid;
      f32x4 acc[4];
#pragma unroll
      for (int ct = 0; ct < 4; ++ct) acc[ct] = bcast4(b2v[ct]);
#pragma unroll
      for (int dw = 0; dw < 3; ++dw) {
        FragU a;
        a.q = *(const uint4*)(&sm.pool1[j + dw][n][quad * 8]);
#pragma unroll
        for (int ct = 0; ct < 4; ++ct) acc[ct] = MFMA16(a.v, B2[dw][ct].v, acc[ct], 0, 0, 0);
      }
#pragma unroll
      for (int r = 0; r < 4; ++r) {
        int veh = quad * 4 + r;
        float m0 = fmaxf(acc[0][r], 0.f), m1 = fmaxf(acc[1][r], 0.f);
        float m2 = fmaxf(acc[2][r], 0.f), m3 = fmaxf(acc[3][r], 0.f);
        uint2 w2; w2.x = pkbf(m0, m1); w2.y = pkbf(m2, m3);
        if (j == 10) *(uint2*)(&sm.pool2[veh][5 * 64 + 4 * n]) = w2;
        else         *(uint2*)(&sm.raw2[j - 8][veh][4 * n]) = w2;
      }
    }
    __syncthreads();

    // ---- stage 4: dense2 partials ----
    {
      f32x4 acc = bcast4((wid == 0) ? d2bv : 0.f);
#pragma unroll
      for (int i = 0; i < 2; ++i)
        if (i < nkt) {
          int kt = (wid < 4) ? (2 * wid + i) : (4 + wid);
          FragU a;
          if (kt == 8 || kt == 9) {    // pool jp4 = max(raw rows 8,9) at load
            int half = kt & 1;
            uint4 r0 = *(const uint4*)(&sm.raw2[0][n][half * 32 + quad * 8]);
            uint4 r1 = *(const uint4*)(&sm.raw2[1][n][half * 32 + quad * 8]);
            a.q.x = pk_umax16(r0.x, r1.x); a.q.y = pk_umax16(r0.y, r1.y);
            a.q.z = pk_umax16(r0.z, r1.z); a.q.w = pk_umax16(r0.w, r1.w);
          } else {
            a.q = *(const uint4*)(&sm.pool2[n][kt * 32 + quad * 8]);
          }
          acc = MFMA16(a.v, Bd[i].v, acc, 0, 0, 0);
        }
      if (n < 10) {
#pragma unroll
        for (int r = 0; r < 4; ++r) sm.dpart[wid][quad * 4 + r][n] = acc[r];
      }
    }
    __syncthreads();

    // ---- stage 5: reduce + dense1 + state update + output + new x-column ----
    if (tid < 256) {
      int o = tid & 15;
      float s = 0.f;
      if (o < 10) {
        float acc = 0.f;
#pragma unroll
        for (int j = 0; j < 8; ++j) acc += sm.dpart[j][vv][o];
        s = fmaxf(acc, 0.f) * wd1v;
      }
      s += __shfl_xor(s, 1, 64);
      s += __shfl_xor(s, 2, 64);
      s += __shfl_xor(s, 4, 64);
      s += __shfl_xor(s, 8, 64);
      if (is_writer) {
        float accv = 10.f * (s + bd1v) - 6.f;          // (MAXA-MINA)*x + MINA
        float np_s = pos_s + 0.02f * spd_s;            // scaled pos + DT*spd
        float nsp = spd_s * 40.f + 0.1f * accv;        // raw new speed
        pos_s = np_s; spd_s = nsp * 0.025f;
        float2 o2; o2.x = np_s * 200.f; o2.y = nsp;
        *(float2*)(out + ((size_t)(vbase + vv) * nt + t) * 2) = o2;
        // append x-column for u_new
        float x0 = lead_nxt.x * 0.005f - np_s;
        uint32_t hi = f2bf(x0);
        uint32_t lo = f2bf(x0 - bf2f(hi));
        uint2 cc;
        cc.x = hi | (f2bf(spd_s) << 16);
        cc.y = f2bf(lead_nxt.y * 0.025f) | (lo << 16);
        *(uint2*)(&sm.Xcol[vv][u_new & 31][0]) = cc;
      }
    }
    __syncthreads();
  }
}

extern "C" void kernel_launch(void* const* d_in, const int* in_sizes, int n_in,
                              void* d_out, int out_size, void* d_ws, size_t ws_size,
                              hipStream_t stream) {
  const float* lead = (const float*)d_in[0];
  const float* cur  = (const float*)d_in[1];
  // d_in[2] = mask (unused by reference)
  const float* c1w = (const float*)d_in[3];
  const float* c1b = (const float*)d_in[4];
  const float* c2w = (const float*)d_in[5];
  const float* c2b = (const float*)d_in[6];
  const float* d2w = (const float*)d_in[7];
  const float* d2b = (const float*)d_in[8];
  const float* d1w = (const float*)d_in[9];
  const float* d1b = (const float*)d_in[10];
  float* out = (float*)d_out;

  int nveh = in_sizes[1] / (PAST * 2);   // 4096
  int ntw  = in_sizes[2] / nveh;         // nt + PAST - 1
  int nt   = ntw - PAST + 1;             // 256
  int nblocks = nveh / 16;               // 256

  rnncf_kernel<<<nblocks, 512, 0, stream>>>(lead, cur, c1w, c1b, c2w, c2b,
                                            d2w, d2b, d1w, d1b, out, nt, ntw);
}